// Round 4
// baseline (79.298 us; speedup 1.0000x reference)
//
#include <hip/hip_runtime.h>

#define MDIM 512
#define LDIM 31
#define WDIM 542            // MDIM + LDIM - 1
#define ROW_IN (MDIM*LDIM)  // 15872 floats per (b,r) row
#define NROWS 2048          // B * MDIM
#define BLK_C 256
#define NCH 3
#define NR 290              // staged rows m in [c0-32, c0+257]
#define SX 8990             // NR*LDIM
#define SX4 2248            // ceil(SX/4)
#define NSLOT 8

__device__ __forceinline__ float wave_max(float v) {
    #pragma unroll
    for (int off = 32; off > 0; off >>= 1)
        v = fmaxf(v, __shfl_xor(v, off));
    return v;
}

__device__ __forceinline__ float sigmoid10(float h) {
    return 1.0f / (1.0f + __expf(-10.0f * h));
}

__global__ void kInit(unsigned int* g) {
    const int t = threadIdx.x;
    for (int i = t; i < NSLOT * 32; i += 256) g[i] = 0u;
}

// g[c] = sum_i Hs[c-i]*x[c-i][i], i=0..30. s_hs/s_x are zero outside valid m.
__device__ __forceinline__ float compute_g(int c, int rlo,
                                           const float* __restrict__ s_hs,
                                           const float* __restrict__ s_x) {
    const float* hb = s_hs + (c - rlo);            // hb[-i]   = Hs[c-i]
    const float* xb = s_x + (c - rlo) * LDIM;      // xb[-30i] = x[c-i][i]
    float a0 = 0.f, a1 = 0.f, a2 = 0.f, a3 = 0.f;
    #pragma unroll
    for (int i = 0; i < 28; i += 4) {
        a0 = fmaf(hb[-i],     xb[-30 * i],       a0);
        a1 = fmaf(hb[-i - 1], xb[-30 * (i + 1)], a1);
        a2 = fmaf(hb[-i - 2], xb[-30 * (i + 2)], a2);
        a3 = fmaf(hb[-i - 3], xb[-30 * (i + 3)], a3);
    }
    a0 = fmaf(hb[-28], xb[-840], a0);
    a1 = fmaf(hb[-29], xb[-870], a1);
    a2 = fmaf(hb[-30], xb[-900], a2);
    return (a0 + a1) + (a2 + a3);
}

__device__ __forceinline__ float yval(int ys, int c, int rlo,
                                      const float* __restrict__ s_hs,
                                      const float* __restrict__ s_x,
                                      const float* __restrict__ s_g) {
    const int rb = c - 31 - rlo;   // >= 0 for all tasks
    const int rc = c + 1 - rlo;    // <= NR-1 for all tasks
    const float B = s_hs[rb] * s_x[rb * LDIM + 30];
    const float C = s_hs[rc] * s_x[rc * LDIM];
    return 0.5f * s_g[ys + 1] + 0.25f * (s_g[ys] - B) + 0.25f * (s_g[ys + 2] - C);
}

__global__ __launch_bounds__(256, 4) void kMain(const float* __restrict__ inp,
                                                const float* __restrict__ H,
                                                float* __restrict__ y_out,
                                                unsigned int* __restrict__ slots) {
    __shared__ __align__(16) float s_x[SX4 * 4];   // 35968 B
    __shared__ float s_hs[NR];                     // 1160 B
    __shared__ float s_m4[NR];                     // 1160 B (4-wide running max of hs)
    __shared__ float s_g[BLK_C + 4];
    __shared__ float s_y[BLK_C + 2];
    __shared__ float s_red[8];
    // total ~40.4 KB -> 4 blocks/CU

    const int chunk = blockIdx.x;
    const int br    = blockIdx.y;
    const int r     = br & (MDIM - 1);
    const int t     = threadIdx.x;
    const int c0    = chunk * BLK_C;
    const int rlo   = c0 - 32;

    // ---- stage x window: 9 unrolled float4 loads; fully-OOB -> zero (no load) ----
    {
        const float4* row4 = (const float4*)(inp + (size_t)br * ROW_IN);
        const int g4start = (rlo * LDIM) >> 2;     // rlo*31 divisible by 4
        const int lo4 = (g4start < 0) ? -g4start : 0;
        const int hi4v = ROW_IN / 4 - g4start;
        const int hi4 = (hi4v < SX4) ? hi4v : SX4;
        float4 v[9];
        #pragma unroll
        for (int j = 0; j < 9; ++j) {
            const int idx = t + 256 * j;
            v[j] = make_float4(0.f, 0.f, 0.f, 0.f);
            if (idx >= lo4 && idx < hi4) v[j] = row4[g4start + idx];
        }
        #pragma unroll
        for (int j = 0; j < 9; ++j) {
            const int idx = t + 256 * j;
            if (idx < SX4) ((float4*)s_x)[idx] = v[j];
        }
    }
    // ---- stage Hs window (zero outside [0, MDIM)) ----
    {
        const float* hrow = H + (size_t)r * MDIM;
        #pragma unroll
        for (int j = 0; j < 2; ++j) {
            const int idx = t + 256 * j;
            if (idx < NR) {
                const int m = rlo + idx;
                s_hs[idx] = (m >= 0 && m < MDIM) ? sigmoid10(hrow[m]) : 0.f;
            }
        }
    }
    __syncthreads();

    // ---- g phase: s_g[gt] <-> c = c0 - 2 + gt, gt in [0, 260) ----
    // guard c <= WDIM+1 (543): chunk-2 waves 1..3 idle
    {
        const int cg = c0 + t;
        if (cg < WDIM + 2) s_g[t + 2] = compute_g(cg, rlo, s_hs, s_x);
        if (t < 2)         s_g[t]     = compute_g(c0 - 2 + t, rlo, s_hs, s_x);
        else if (t >= 254 && c0 + t + 2 < WDIM + 2)
                           s_g[t + 4] = compute_g(c0 + t + 2, rlo, s_hs, s_x);
    }
    __syncthreads();

    // ---- y phase: s_y[ys] <-> c = c0 - 1 + ys ----
    float lmaxy = 0.f;
    {
        const int c = c0 + t;
        if (c <= WDIM) {
            const float yv = yval(t + 1, c, rlo, s_hs, s_x, s_g);
            s_y[t + 1] = yv;
            if (c < WDIM) {
                y_out[(size_t)br * WDIM + c] = yv;
                lmaxy = yv;
            }
        }
        if (t == 0)   s_y[0] = yval(0, c0 - 1, rlo, s_hs, s_x, s_g);
        if (t == 255 && c0 + 256 <= WDIM)
                      s_y[257] = yval(257, c0 + 256, rlo, s_hs, s_x, s_g);
    }
    // ---- build M4[idx] = max(hs[idx..idx+3]) (reads s_hs, writes s_m4) ----
    #pragma unroll
    for (int j = 0; j < 2; ++j) {
        const int idx = t + 256 * j;
        if (idx < NR - 3)
            s_m4[idx] = fmaxf(fmaxf(s_hs[idx], s_hs[idx + 1]),
                              fmaxf(s_hs[idx + 2], s_hs[idx + 3]));
    }
    __syncthreads();

    // ---- Z-max phase: e = c0 + t; window-29 max via M4 blocks ----
    float lmaxz = 0.f;
    if (c0 + t < WDIM) {
        const float yl = s_y[t], ym = s_y[t + 1], yr = s_y[t + 2];
        const float wf  = 0.25f * yl + 0.5f * ym + 0.25f * yr;  // l in [1,29]
        const float w0  = 0.5f * ym + 0.25f * yr;               // l = 0
        const float w30 = 0.25f * yl + 0.5f * ym;               // l = 30
        // max Hs over idx [t+3, t+31]: 7 M4 blocks + 1 scalar
        const float hm = fmaxf(
            fmaxf(fmaxf(s_m4[t + 3],  s_m4[t + 7]),
                  fmaxf(s_m4[t + 11], s_m4[t + 15])),
            fmaxf(fmaxf(s_m4[t + 19], s_m4[t + 23]),
                  fmaxf(s_m4[t + 27], s_hs[t + 31])));
        lmaxz = fmaxf(wf * hm, fmaxf(w0 * s_hs[t + 32], w30 * s_hs[t + 2]));
    }

    // ---- block reduce + hashed-slot atomics ----
    const float wy = wave_max(lmaxy);
    const float wz = wave_max(lmaxz);
    const int wv = t >> 6, ln = t & 63;
    if (ln == 0) { s_red[wv] = wy; s_red[4 + wv] = wz; }
    __syncthreads();
    if (t == 0) {
        const float my = fmaxf(fmaxf(s_red[0], s_red[1]), fmaxf(s_red[2], s_red[3]));
        const float mz = fmaxf(fmaxf(s_red[4], s_red[5]), fmaxf(s_red[6], s_red[7]));
        const int slot = br & (NSLOT - 1);
        atomicMax(&slots[slot * 32],      __float_as_uint(my));
        atomicMax(&slots[slot * 32 + 16], __float_as_uint(mz));
    }
}

// One block per (b, r) row. Writes Xout (normalized Z), normalizes its own
// y row in place, and (b==0) writes Hs. Inlines the 8-slot max reduce.
__global__ __launch_bounds__(256) void kB(const float* __restrict__ H,
                                          float* __restrict__ out,
                                          const unsigned int* __restrict__ slots) {
    __shared__ float s_y[WDIM];
    __shared__ float s_wyf[WDIM];
    __shared__ float s_hs[MDIM];

    const int br  = blockIdx.x;
    const int b   = br >> 9;
    const int r   = br & (MDIM - 1);
    const int tid = threadIdx.x;

    float* xout  = out;                                   // [NROWS][ROW_IN]
    float* yout  = out + (size_t)NROWS * ROW_IN;          // [NROWS][WDIM]
    float* hsout = yout + (size_t)NROWS * WDIM;           // [MDIM*MDIM]

    for (int t = tid; t < WDIM; t += 256) s_y[t] = yout[(size_t)br * WDIM + t];
    const float* hrow = H + (size_t)r * MDIM;
    for (int t = tid; t < MDIM; t += 256) s_hs[t] = sigmoid10(hrow[t]);
    __syncthreads();

    // wyf[e] = 0.25*y[e-1] + 0.5*y[e] + 0.25*y[e+1] (interior-l blur)
    for (int e = tid; e < WDIM; e += 256) {
        const float yl = (e > 0) ? s_y[e - 1] : 0.f;
        const float yr = (e < WDIM - 1) ? s_y[e + 1] : 0.f;
        s_wyf[e] = 0.25f * yl + 0.5f * s_y[e] + 0.25f * yr;
    }

    // inline slot reduce (all threads, broadcast loads)
    float my = 0.f, mz = 0.f;
    #pragma unroll
    for (int s = 0; s < NSLOT; ++s) {
        my = fmaxf(my, __uint_as_float(slots[s * 32]));
        mz = fmaxf(mz, __uint_as_float(slots[s * 32 + 16]));
    }
    const float inv_my = 1.0f / my;
    const float inv_mz = 1.0f / mz;
    __syncthreads();

    float4* xr4 = (float4*)(xout + (size_t)br * ROW_IN);
    for (int t4 = tid; t4 < ROW_IN / 4; t4 += 256) {
        const int e0 = 4 * t4;
        int m = e0 / LDIM;           // one magic-mul div per group of 4
        int l = e0 - m * LDIM;
        float h = s_hs[m];
        float vals[4];
        #pragma unroll
        for (int j = 0; j < 4; ++j) {
            float v;
            if (l == 0)            v = 0.5f * s_y[m] + 0.25f * s_y[m + 1];
            else if (l == LDIM-1)  v = 0.25f * s_y[m + 29] + 0.5f * s_y[m + 30];
            else                   v = s_wyf[m + l];
            vals[j] = v * h * inv_mz;
            if (++l == LDIM) { l = 0; ++m; h = (m < MDIM) ? s_hs[m] : 0.f; }
        }
        float4 o; o.x = vals[0]; o.y = vals[1]; o.z = vals[2]; o.w = vals[3];
        xr4[t4] = o;
    }

    for (int t = tid; t < WDIM; t += 256)
        yout[(size_t)br * WDIM + t] = s_y[t] * inv_my;

    if (b == 0)
        for (int t = tid; t < MDIM; t += 256)
            hsout[(size_t)r * MDIM + t] = s_hs[t];
}

extern "C" void kernel_launch(void* const* d_in, const int* in_sizes, int n_in,
                              void* d_out, int out_size, void* d_ws, size_t ws_size,
                              hipStream_t stream) {
    const float* inp = (const float*)d_in[0];   // (4,512,512,31) f32
    const float* H   = (const float*)d_in[1];   // (1,512,512,1,1) f32
    float* out = (float*)d_out;
    unsigned int* slots = (unsigned int*)d_ws;  // 8 cacheline-padded max slots
    float* yraw = out + (size_t)NROWS * ROW_IN; // y slot: raw from kMain, normalized by kB

    hipLaunchKernelGGL(kInit, dim3(1), dim3(256), 0, stream, slots);
    hipLaunchKernelGGL(kMain, dim3(NCH, NROWS), dim3(256), 0, stream, inp, H, yraw, slots);
    hipLaunchKernelGGL(kB, dim3(NROWS), dim3(256), 0, stream, H, out, slots);
}

// Round 5
// 70.986 us; speedup vs baseline: 1.1171x; 1.1171x over previous
//
#include <hip/hip_runtime.h>

#define MDIM 512
#define LDIM 31
#define WDIM 542            // MDIM + LDIM - 1
#define ROW_IN (MDIM*LDIM)  // 15872 floats per (b,r) row
#define NROWS 2048          // B * MDIM
#define BLK_C 256
#define NCH 3
#define NR 290              // staged rows m in [c0-32, c0+257]
#define SX 8990             // NR*LDIM
#define SX4 2248            // ceil(SX/4)
#define NSLOT 8

__device__ __forceinline__ float wave_max(float v) {
    #pragma unroll
    for (int off = 32; off > 0; off >>= 1)
        v = fmaxf(v, __shfl_xor(v, off));
    return v;
}

__device__ __forceinline__ float sigmoid10(float h) {
    return 1.0f / (1.0f + __expf(-10.0f * h));
}

__global__ void kInit(unsigned int* g) {
    const int t = threadIdx.x;
    for (int i = t; i < NSLOT * 32; i += 256) g[i] = 0u;
}

// g[c] = sum_i Hs[c-i]*x[c-i][i], i=0..30. s_hs/s_x are zero outside valid m.
__device__ __forceinline__ float compute_g(int c, int rlo,
                                           const float* __restrict__ s_hs,
                                           const float* __restrict__ s_x) {
    const float* hb = s_hs + (c - rlo);            // hb[-i]   = Hs[c-i]
    const float* xb = s_x + (c - rlo) * LDIM;      // xb[-30i] = x[c-i][i]
    float a0 = 0.f, a1 = 0.f, a2 = 0.f, a3 = 0.f;
    #pragma unroll
    for (int i = 0; i < 28; i += 4) {
        a0 = fmaf(hb[-i],     xb[-30 * i],       a0);
        a1 = fmaf(hb[-i - 1], xb[-30 * (i + 1)], a1);
        a2 = fmaf(hb[-i - 2], xb[-30 * (i + 2)], a2);
        a3 = fmaf(hb[-i - 3], xb[-30 * (i + 3)], a3);
    }
    a0 = fmaf(hb[-28], xb[-840], a0);
    a1 = fmaf(hb[-29], xb[-870], a1);
    a2 = fmaf(hb[-30], xb[-900], a2);
    return (a0 + a1) + (a2 + a3);
}

__device__ __forceinline__ float yval(int ys, int c, int rlo,
                                      const float* __restrict__ s_hs,
                                      const float* __restrict__ s_x,
                                      const float* __restrict__ s_g) {
    const int rb = c - 31 - rlo;   // >= 0 for all tasks
    const int rc = c + 1 - rlo;    // <= NR-1 for all tasks
    const float B = s_hs[rb] * s_x[rb * LDIM + 30];
    const float C = s_hs[rc] * s_x[rc * LDIM];
    return 0.5f * s_g[ys + 1] + 0.25f * (s_g[ys] - B) + 0.25f * (s_g[ys + 2] - C);
}

__global__ __launch_bounds__(256, 4) void kMain(const float* __restrict__ inp,
                                                const float* __restrict__ H,
                                                float* __restrict__ y_out,
                                                unsigned int* __restrict__ slots) {
    __shared__ __align__(16) float s_x[SX4 * 4];   // 35968 B
    __shared__ float s_hs[NR];                     // 1160 B
    __shared__ float s_g[BLK_C + 4];
    __shared__ float s_y[BLK_C + 2];
    __shared__ float s_red[8];

    const int chunk = blockIdx.x;
    const int br    = blockIdx.y;
    const int r     = br & (MDIM - 1);
    const int t     = threadIdx.x;
    const int c0    = chunk * BLK_C;
    const int rlo   = c0 - 32;

    // ---- stage x window: 9 unrolled float4 loads; fully-OOB -> zero (no load) ----
    {
        const float4* row4 = (const float4*)(inp + (size_t)br * ROW_IN);
        const int g4start = (rlo * LDIM) >> 2;     // rlo*31 divisible by 4
        const int lo4 = (g4start < 0) ? -g4start : 0;
        const int hi4v = ROW_IN / 4 - g4start;
        const int hi4 = (hi4v < SX4) ? hi4v : SX4;
        float4 v[9];
        #pragma unroll
        for (int j = 0; j < 9; ++j) {
            const int idx = t + 256 * j;
            v[j] = make_float4(0.f, 0.f, 0.f, 0.f);
            if (idx >= lo4 && idx < hi4) v[j] = row4[g4start + idx];
        }
        #pragma unroll
        for (int j = 0; j < 9; ++j) {
            const int idx = t + 256 * j;
            if (idx < SX4) ((float4*)s_x)[idx] = v[j];
        }
    }
    // ---- stage Hs window (zero outside [0, MDIM)) ----
    {
        const float* hrow = H + (size_t)r * MDIM;
        #pragma unroll
        for (int j = 0; j < 2; ++j) {
            const int idx = t + 256 * j;
            if (idx < NR) {
                const int m = rlo + idx;
                s_hs[idx] = (m >= 0 && m < MDIM) ? sigmoid10(hrow[m]) : 0.f;
            }
        }
    }
    __syncthreads();

    // ---- g phase: s_g[gt] <-> c = c0 - 2 + gt, gt in [0, 260) ----
    {
        const int cg = c0 + t;
        if (cg < WDIM + 2) s_g[t + 2] = compute_g(cg, rlo, s_hs, s_x);
        if (t < 2)         s_g[t]     = compute_g(c0 - 2 + t, rlo, s_hs, s_x);
        else if (t >= 254 && c0 + t + 2 < WDIM + 2)
                           s_g[t + 4] = compute_g(c0 + t + 2, rlo, s_hs, s_x);
    }
    __syncthreads();

    // ---- y phase: s_y[ys] <-> c = c0 - 1 + ys ----
    float lmaxy = 0.f;
    {
        const int c = c0 + t;
        if (c <= WDIM) {
            const float yv = yval(t + 1, c, rlo, s_hs, s_x, s_g);
            s_y[t + 1] = yv;
            if (c < WDIM) {
                y_out[(size_t)br * WDIM + c] = yv;
                lmaxy = yv;
            }
        }
        if (t == 0)   s_y[0] = yval(0, c0 - 1, rlo, s_hs, s_x, s_g);
        if (t == 255 && c0 + 256 <= WDIM)
                      s_y[257] = yval(257, c0 + 256, rlo, s_hs, s_x, s_g);
    }
    __syncthreads();

    // ---- Z-max phase: e = c0 + t ----
    float lmaxz = 0.f;
    if (c0 + t < WDIM) {
        const float yl = s_y[t], ym = s_y[t + 1], yr = s_y[t + 2];
        const float wf  = 0.25f * yl + 0.5f * ym + 0.25f * yr;  // l in [1,29]
        const float w0  = 0.5f * ym + 0.25f * yr;               // l = 0
        const float w30 = 0.25f * yl + 0.5f * ym;               // l = 30
        float hm = s_hs[t + 3];                                 // l=29
        #pragma unroll
        for (int j = 4; j <= 31; ++j) hm = fmaxf(hm, s_hs[t + j]);
        lmaxz = fmaxf(wf * hm, fmaxf(w0 * s_hs[t + 32], w30 * s_hs[t + 2]));
    }

    // ---- block reduce + hashed-slot atomics ----
    const float wy = wave_max(lmaxy);
    const float wz = wave_max(lmaxz);
    const int wv = t >> 6, ln = t & 63;
    if (ln == 0) { s_red[wv] = wy; s_red[4 + wv] = wz; }
    __syncthreads();
    if (t == 0) {
        const float my = fmaxf(fmaxf(s_red[0], s_red[1]), fmaxf(s_red[2], s_red[3]));
        const float mz = fmaxf(fmaxf(s_red[4], s_red[5]), fmaxf(s_red[6], s_red[7]));
        const int slot = br & (NSLOT - 1);
        atomicMax(&slots[slot * 32],      __float_as_uint(my));
        atomicMax(&slots[slot * 32 + 16], __float_as_uint(mz));
    }
}

// One block per (b, r) row. Writes Xout (normalized Z), normalizes its own
// y row in place, and (b==0) writes Hs. Inlines the 8-slot max reduce.
__global__ __launch_bounds__(256) void kB(const float* __restrict__ H,
                                          float* __restrict__ out,
                                          const unsigned int* __restrict__ slots) {
    __shared__ float s_y[WDIM];
    __shared__ float s_hs[MDIM];

    const int br  = blockIdx.x;
    const int b   = br >> 9;
    const int r   = br & (MDIM - 1);
    const int tid = threadIdx.x;

    float* xout  = out;                                   // [NROWS][ROW_IN]
    float* yout  = out + (size_t)NROWS * ROW_IN;          // [NROWS][WDIM]
    float* hsout = yout + (size_t)NROWS * WDIM;           // [MDIM*MDIM]

    for (int t = tid; t < WDIM; t += 256) s_y[t] = yout[(size_t)br * WDIM + t];
    const float* hrow = H + (size_t)r * MDIM;
    for (int t = tid; t < MDIM; t += 256) s_hs[t] = sigmoid10(hrow[t]);

    // inline slot reduce (all threads, broadcast loads)
    float my = 0.f, mz = 0.f;
    #pragma unroll
    for (int s = 0; s < NSLOT; ++s) {
        my = fmaxf(my, __uint_as_float(slots[s * 32]));
        mz = fmaxf(mz, __uint_as_float(slots[s * 32 + 16]));
    }
    const float inv_my = 1.0f / my;
    const float inv_mz = 1.0f / mz;
    __syncthreads();

    float4* xr4 = (float4*)(xout + (size_t)br * ROW_IN);
    for (int t4 = tid; t4 < ROW_IN / 4; t4 += 256) {
        const int e = t4 * 4;
        float vals[4];
        #pragma unroll
        for (int j = 0; j < 4; ++j) {
            const int idx = e + j;
            const int m = idx / LDIM;
            const int l = idx - m * LDIM;
            float v = 0.5f * s_y[m + l];
            if (l > 0)        v += 0.25f * s_y[m + l - 1];
            if (l < LDIM - 1) v += 0.25f * s_y[m + l + 1];
            vals[j] = v * s_hs[m] * inv_mz;
        }
        float4 o; o.x = vals[0]; o.y = vals[1]; o.z = vals[2]; o.w = vals[3];
        xr4[t4] = o;
    }

    for (int t = tid; t < WDIM; t += 256)
        yout[(size_t)br * WDIM + t] = s_y[t] * inv_my;

    if (b == 0)
        for (int t = tid; t < MDIM; t += 256)
            hsout[(size_t)r * MDIM + t] = s_hs[t];
}

extern "C" void kernel_launch(void* const* d_in, const int* in_sizes, int n_in,
                              void* d_out, int out_size, void* d_ws, size_t ws_size,
                              hipStream_t stream) {
    const float* inp = (const float*)d_in[0];   // (4,512,512,31) f32
    const float* H   = (const float*)d_in[1];   // (1,512,512,1,1) f32
    float* out = (float*)d_out;
    unsigned int* slots = (unsigned int*)d_ws;  // 8 cacheline-padded max slots
    float* yraw = out + (size_t)NROWS * ROW_IN; // y slot: raw from kMain, normalized by kB

    hipLaunchKernelGGL(kInit, dim3(1), dim3(256), 0, stream, slots);
    hipLaunchKernelGGL(kMain, dim3(NCH, NROWS), dim3(256), 0, stream, inp, H, yraw, slots);
    hipLaunchKernelGGL(kB, dim3(NROWS), dim3(256), 0, stream, H, out, slots);
}

// Round 8
// 64.887 us; speedup vs baseline: 1.2221x; 1.0940x over previous
//
#include <hip/hip_runtime.h>

#define MDIM 512
#define LDIM 31
#define WDIM 542            // MDIM + LDIM - 1
#define ROW_IN (MDIM*LDIM)  // 15872 floats per (b,r) row
#define NROWS 2048          // B * MDIM
#define BLK_C 192           // c-values per chunk (3*192 = 576 >= 542)
#define NCH 3
#define NR 226              // staged rows m in [c0-32, c0+193]
#define SX4 1752            // ceil(NR*31/4) = ceil(7006/4)
#define NLD 7               // ceil(SX4/256)
#define NSLOT 8

__device__ __forceinline__ float wave_max(float v) {
    #pragma unroll
    for (int off = 32; off > 0; off >>= 1)
        v = fmaxf(v, __shfl_xor(v, off));
    return v;
}

__device__ __forceinline__ float sigmoid10(float h) {
    return 1.0f / (1.0f + __expf(-10.0f * h));
}

__global__ void kInit(unsigned int* g) {
    const int t = threadIdx.x;
    if (t < NSLOT * 32) g[t] = 0u;
}

// g[c] = sum_i Hs[c-i]*x[c-i][i], i=0..30. s_hs/s_x are zero outside valid m.
__device__ __forceinline__ float compute_g(int c, int rlo,
                                           const float* __restrict__ s_hs,
                                           const float* __restrict__ s_x) {
    const float* hb = s_hs + (c - rlo);            // hb[-i]   = Hs[c-i]
    const float* xb = s_x + (c - rlo) * LDIM;      // xb[-30i] = x[c-i][i]
    float a0 = 0.f, a1 = 0.f, a2 = 0.f, a3 = 0.f;
    #pragma unroll
    for (int i = 0; i < 28; i += 4) {
        a0 = fmaf(hb[-i],     xb[-30 * i],       a0);
        a1 = fmaf(hb[-i - 1], xb[-30 * (i + 1)], a1);
        a2 = fmaf(hb[-i - 2], xb[-30 * (i + 2)], a2);
        a3 = fmaf(hb[-i - 3], xb[-30 * (i + 3)], a3);
    }
    a0 = fmaf(hb[-28], xb[-840], a0);
    a1 = fmaf(hb[-29], xb[-870], a1);
    a2 = fmaf(hb[-30], xb[-900], a2);
    return (a0 + a1) + (a2 + a3);
}

// s_g[gt] = g(c0-2+gt); ys = (c - (c0-1)).
__device__ __forceinline__ float yval(int ys, int c, int rlo,
                                      const float* __restrict__ s_hs,
                                      const float* __restrict__ s_x,
                                      const float* __restrict__ s_g) {
    const int rb = c - 31 - rlo;   // >= 0 for all tasks
    const int rc = c + 1 - rlo;    // <= NR-1 for all tasks
    const float B = s_hs[rb] * s_x[rb * LDIM + 30];
    const float C = s_hs[rc] * s_x[rc * LDIM];
    return 0.5f * s_g[ys + 1] + 0.25f * (s_g[ys] - B) + 0.25f * (s_g[ys + 2] - C);
}

__global__ __launch_bounds__(256, 5) void kMain(const float* __restrict__ inp,
                                                const float* __restrict__ H,
                                                float* __restrict__ y_out,
                                                unsigned int* __restrict__ slots) {
    __shared__ __align__(16) float s_x[SX4 * 4];   // 28032 B
    __shared__ float s_hs[NR];                     // 904 B
    __shared__ float s_g[BLK_C + 4];               // 196 entries: g[c0-2 .. c0+193]
    __shared__ float s_y[BLK_C + 2];               // 194 entries: y[c0-1 .. c0+192]
    __shared__ float s_red[8];
    // total ~30.5 KB -> 5 blocks/CU

    const int chunk = blockIdx.x;
    const int br    = blockIdx.y;
    const int r     = br & (MDIM - 1);
    const int t     = threadIdx.x;
    const int c0    = chunk * BLK_C;
    const int rlo   = c0 - 32;

    // ---- stage x window: 7 unrolled float4 loads; fully-OOB -> zero (no load) ----
    {
        const float4* row4 = (const float4*)(inp + (size_t)br * ROW_IN);
        const int g4start = (rlo * LDIM) >> 2;     // rlo*31 divisible by 4
        const int lo4 = (g4start < 0) ? -g4start : 0;
        int hi4 = ROW_IN / 4 - g4start; if (hi4 > SX4) hi4 = SX4;
        float4 v[NLD];
        #pragma unroll
        for (int j = 0; j < NLD; ++j) {
            const int idx = t + 256 * j;
            v[j] = make_float4(0.f, 0.f, 0.f, 0.f);
            if (idx >= lo4 && idx < hi4) v[j] = row4[g4start + idx];
        }
        #pragma unroll
        for (int j = 0; j < NLD; ++j) {
            const int idx = t + 256 * j;
            if (idx < SX4) ((float4*)s_x)[idx] = v[j];
        }
    }
    // ---- stage Hs window (zero outside [0, MDIM)); NR=226 <= 256, one pass ----
    if (t < NR) {
        const int m = rlo + t;
        s_hs[t] = (m >= 0 && m < MDIM)
                  ? sigmoid10(H[(size_t)r * MDIM + m]) : 0.f;
    }
    __syncthreads();

    // ---- g phase: s_g[t] = g(c0-2+t), t < 196, c <= 543 ----
    {
        const int c = c0 - 2 + t;
        if (t < BLK_C + 4 && c <= WDIM + 1)
            s_g[t] = compute_g(c, rlo, s_hs, s_x);
    }
    __syncthreads();

    // ---- y phase: t <= 192 covers c = c0+t (incl. right edge y[c0+192]) ----
    float lmaxy = 0.f;
    {
        const int c = c0 + t;
        if (t <= BLK_C && c <= WDIM) {
            const float yv = yval(t + 1, c, rlo, s_hs, s_x, s_g);
            s_y[t + 1] = yv;
            if (t < BLK_C && c < WDIM) {
                y_out[(size_t)br * WDIM + c] = yv;
                lmaxy = yv;
            }
        }
        if (t == 0) s_y[0] = yval(0, c0 - 1, rlo, s_hs, s_x, s_g);
    }
    __syncthreads();

    // ---- Z-max phase: e = c0 + t, t < 192 ----
    float lmaxz = 0.f;
    if (t < BLK_C && c0 + t < WDIM) {
        const float yl = s_y[t], ym = s_y[t + 1], yr = s_y[t + 2];
        const float wf  = 0.25f * yl + 0.5f * ym + 0.25f * yr;  // l in [1,29]
        const float w0  = 0.5f * ym + 0.25f * yr;               // l = 0
        const float w30 = 0.25f * yl + 0.5f * ym;               // l = 30
        float hm = s_hs[t + 3];                                 // Hs[e-29]
        #pragma unroll
        for (int j = 4; j <= 31; ++j) hm = fmaxf(hm, s_hs[t + j]);
        lmaxz = fmaxf(wf * hm, fmaxf(w0 * s_hs[t + 32], w30 * s_hs[t + 2]));
    }

    // ---- block reduce + hashed-slot atomics ----
    const float wy = wave_max(lmaxy);
    const float wz = wave_max(lmaxz);
    const int wv = t >> 6, ln = t & 63;
    if (ln == 0) { s_red[wv] = wy; s_red[4 + wv] = wz; }
    __syncthreads();
    if (t == 0) {
        const float my = fmaxf(fmaxf(s_red[0], s_red[1]), fmaxf(s_red[2], s_red[3]));
        const float mz = fmaxf(fmaxf(s_red[4], s_red[5]), fmaxf(s_red[6], s_red[7]));
        const int slot = br & (NSLOT - 1);
        atomicMax(&slots[slot * 32],      __float_as_uint(my));
        atomicMax(&slots[slot * 32 + 16], __float_as_uint(mz));
    }
}

// One block per (b, r) row. Writes Xout (normalized Z), normalizes its own
// y row in place, and (b==0) writes Hs. Inlines the 8-slot max reduce.
__global__ __launch_bounds__(256) void kB(const float* __restrict__ H,
                                          float* __restrict__ out,
                                          const unsigned int* __restrict__ slots) {
    __shared__ float s_y[WDIM];
    __shared__ float s_hs[MDIM];

    const int br  = blockIdx.x;
    const int b   = br >> 9;
    const int r   = br & (MDIM - 1);
    const int tid = threadIdx.x;

    float* xout  = out;                                   // [NROWS][ROW_IN]
    float* yout  = out + (size_t)NROWS * ROW_IN;          // [NROWS][WDIM]
    float* hsout = yout + (size_t)NROWS * WDIM;           // [MDIM*MDIM]

    for (int t = tid; t < WDIM; t += 256) s_y[t] = yout[(size_t)br * WDIM + t];
    const float* hrow = H + (size_t)r * MDIM;
    for (int t = tid; t < MDIM; t += 256) s_hs[t] = sigmoid10(hrow[t]);

    // inline slot reduce (all threads, broadcast loads)
    float my = 0.f, mz = 0.f;
    #pragma unroll
    for (int s = 0; s < NSLOT; ++s) {
        my = fmaxf(my, __uint_as_float(slots[s * 32]));
        mz = fmaxf(mz, __uint_as_float(slots[s * 32 + 16]));
    }
    const float inv_my = 1.0f / my;
    const float inv_mz = 1.0f / mz;
    __syncthreads();

    float4* xr4 = (float4*)(xout + (size_t)br * ROW_IN);
    for (int t4 = tid; t4 < ROW_IN / 4; t4 += 256) {
        const int e = t4 * 4;
        float vals[4];
        #pragma unroll
        for (int j = 0; j < 4; ++j) {
            const int idx = e + j;
            const int m = idx / LDIM;
            const int l = idx - m * LDIM;
            float v = 0.5f * s_y[m + l];
            if (l > 0)        v += 0.25f * s_y[m + l - 1];
            if (l < LDIM - 1) v += 0.25f * s_y[m + l + 1];
            vals[j] = v * s_hs[m] * inv_mz;
        }
        float4 o; o.x = vals[0]; o.y = vals[1]; o.z = vals[2]; o.w = vals[3];
        xr4[t4] = o;
    }

    for (int t = tid; t < WDIM; t += 256)
        yout[(size_t)br * WDIM + t] = s_y[t] * inv_my;

    if (b == 0)
        for (int t = tid; t < MDIM; t += 256)
            hsout[(size_t)r * MDIM + t] = s_hs[t];
}

extern "C" void kernel_launch(void* const* d_in, const int* in_sizes, int n_in,
                              void* d_out, int out_size, void* d_ws, size_t ws_size,
                              hipStream_t stream) {
    const float* inp = (const float*)d_in[0];   // (4,512,512,31) f32
    const float* H   = (const float*)d_in[1];   // (1,512,512,1,1) f32
    float* out = (float*)d_out;
    unsigned int* slots = (unsigned int*)d_ws;  // 8 cacheline-padded max slots
    float* yraw = out + (size_t)NROWS * ROW_IN; // y slot: raw from kMain, normalized by kB

    hipLaunchKernelGGL(kInit, dim3(1), dim3(256), 0, stream, slots);
    hipLaunchKernelGGL(kMain, dim3(NCH, NROWS), dim3(256), 0, stream, inp, H, yraw, slots);
    hipLaunchKernelGGL(kB, dim3(NROWS), dim3(256), 0, stream, H, out, slots);
}